// Round 1
// baseline (2162.202 us; speedup 1.0000x reference)
//
#include <hip/hip_runtime.h>
#include <math.h>

#define NN 4096
#define EE 131072
#define IN_DIM 512
#define HID 256
#define OUT_DIM 64

// ---------------- reduction helpers ----------------
__device__ __forceinline__ float waveReduceSum(float v){
#pragma unroll
  for (int off = 32; off > 0; off >>= 1) v += __shfl_down(v, off);
  return v;
}

// ---------------- graph build ----------------
__global__ void k_build_A(const int* __restrict__ ei, float* __restrict__ A){
  int e = blockIdx.x * blockDim.x + threadIdx.x;
  if (e < EE){
    int r = ei[e], c = ei[EE + e];
    A[(size_t)r * NN + c] = 1.0f;   // duplicates write same value: deterministic
  }
}

// dinv[i] = 1/sqrt(rowsum(A) + 2)   (Ah = A + 2I)
__global__ void k_dinv(const float* __restrict__ A, float* __restrict__ dinv, int n){
  int row = blockIdx.x;
  float s = 0.f;
  for (int j = threadIdx.x; j < n; j += 256) s += A[(size_t)row * n + j];
  s = waveReduceSum(s);
  __shared__ float sh[4];
  int lane = threadIdx.x & 63, wid = threadIdx.x >> 6;
  if (lane == 0) sh[wid] = s;
  __syncthreads();
  if (threadIdx.x == 0){
    float d = sh[0] + sh[1] + sh[2] + sh[3] + 2.0f;
    dinv[row] = (d > 0.f) ? (1.0f / sqrtf(d)) : 0.0f;
  }
}

// ---------------- dense fp32 GEMM: C = A(MxK) @ B(KxN); M,N %64==0, K %16==0 ----------------
__global__ __launch_bounds__(256) void k_gemm(const float* __restrict__ A,
                                              const float* __restrict__ B,
                                              float* __restrict__ C,
                                              int M, int N, int K){
  __shared__ float As[16][68];
  __shared__ float Bs[16][68];
  const int tx = threadIdx.x & 15, ty = threadIdx.x >> 4;
  const int bm = blockIdx.y << 6, bn = blockIdx.x << 6;
  float acc[4][4] = {{0.f}};
  for (int k0 = 0; k0 < K; k0 += 16){
    for (int t = threadIdx.x; t < 1024; t += 256){
      int m = t >> 4, k = t & 15;
      As[k][m] = A[(size_t)(bm + m) * K + (k0 + k)];
    }
    for (int t = threadIdx.x; t < 1024; t += 256){
      int k = t >> 6, n = t & 63;
      Bs[k][n] = B[(size_t)(k0 + k) * N + (bn + n)];
    }
    __syncthreads();
#pragma unroll
    for (int kk = 0; kk < 16; ++kk){
      float a[4], b[4];
#pragma unroll
      for (int i = 0; i < 4; ++i) a[i] = As[kk][(ty << 2) + i];
#pragma unroll
      for (int j = 0; j < 4; ++j) b[j] = Bs[kk][(tx << 2) + j];
#pragma unroll
      for (int i = 0; i < 4; ++i)
#pragma unroll
        for (int j = 0; j < 4; ++j) acc[i][j] += a[i] * b[j];
    }
    __syncthreads();
  }
#pragma unroll
  for (int i = 0; i < 4; ++i){
    size_t ro = (size_t)(bm + (ty << 2) + i) * N + bn + (tx << 2);
#pragma unroll
    for (int j = 0; j < 4; ++j) C[ro + j] = acc[i][j];
  }
}

// ---------------- sparse-row x dense GEMM ----------------
// C[r][:] = sum_k S[srow][k] * D[k][:]   (+ optionally +1 at k==srow for the +I term)
// srow = rowperm ? rowperm[r] : r.  Deterministic two-pass compaction (no atomics).
#define SP_CAP 1024
template<int CPT>
__global__ __launch_bounds__(256) void k_spmm(const float* __restrict__ S,
                                              const int* __restrict__ rowperm, int plusI,
                                              const float* __restrict__ D,
                                              float* __restrict__ C,
                                              int K, int Ncols){
  int r = blockIdx.x;
  int srow = rowperm ? rowperm[r] : r;
  __shared__ int   s_idx[SP_CAP];
  __shared__ float s_val[SP_CAP];
  __shared__ int   s_cnt[256];
  const float* Srow = S + (size_t)srow * K;
  int cnt = 0;
  for (int k = threadIdx.x; k < K; k += 256) if (Srow[k] != 0.f) cnt++;
  s_cnt[threadIdx.x] = cnt;
  __syncthreads();
  for (int off = 1; off < 256; off <<= 1){
    int a = s_cnt[threadIdx.x];
    int b = (threadIdx.x >= off) ? s_cnt[threadIdx.x - off] : 0;
    __syncthreads();
    s_cnt[threadIdx.x] = a + b;
    __syncthreads();
  }
  int total = s_cnt[255];
  int pos = s_cnt[threadIdx.x] - cnt;
  for (int k = threadIdx.x; k < K; k += 256){
    float v = Srow[k];
    if (v != 0.f){ if (pos < SP_CAP){ s_idx[pos] = k; s_val[pos] = v; } pos++; }
  }
  if (plusI && threadIdx.x == 0 && total < SP_CAP){ s_idx[total] = srow; s_val[total] = 1.0f; }
  __syncthreads();
  int n_nz = total + (plusI ? 1 : 0); if (n_nz > SP_CAP) n_nz = SP_CAP;
  float acc[CPT];
#pragma unroll
  for (int j = 0; j < CPT; ++j) acc[j] = 0.f;
  for (int e = 0; e < n_nz; ++e){
    int k = s_idx[e]; float v = s_val[e];
    const float* Drow = D + (size_t)k * Ncols;
#pragma unroll
    for (int j = 0; j < CPT; ++j){
      int c = threadIdx.x + (j << 8);
      if (c < Ncols) acc[j] += v * Drow[c];
    }
  }
#pragma unroll
  for (int j = 0; j < CPT; ++j){
    int c = threadIdx.x + (j << 8);
    if (c < Ncols) C[(size_t)r * Ncols + c] = acc[j];
  }
}

// ---------------- elementwise / epilogue ----------------
__global__ void k_scale_rows(const float* __restrict__ Z, const float* __restrict__ dinv,
                             float* __restrict__ Zs, int C){
  int row = blockIdx.x; float di = dinv[row];
  for (int c = threadIdx.x; c < C; c += 256)
    Zs[(size_t)row * C + c] = di * Z[(size_t)row * C + c];
}

// out = relu?( dinv[i]*(Y + 2*Zs) + b )
__global__ void k_epilogue(const float* __restrict__ Y, const float* __restrict__ Zs,
                           const float* __restrict__ dinv, const float* __restrict__ b,
                           float* __restrict__ out, int C, int relu){
  int row = blockIdx.x; float di = dinv[row];
  for (int c = threadIdx.x; c < C; c += 256){
    float v = di * (Y[(size_t)row * C + c] + 2.0f * Zs[(size_t)row * C + c]) + b[c];
    out[(size_t)row * C + c] = relu ? fmaxf(v, 0.f) : v;
  }
}

__global__ void k_wnorm(const float* __restrict__ w, float* __restrict__ out){
  float v = w[threadIdx.x]; v *= v;
  v = waveReduceSum(v);
  __shared__ float sh[4];
  int lane = threadIdx.x & 63, wid = threadIdx.x >> 6;
  if (lane == 0) sh[wid] = v;
  __syncthreads();
  if (threadIdx.x == 0) out[0] = sqrtf(sh[0] + sh[1] + sh[2] + sh[3]);
}

__global__ void k_score(const float* __restrict__ x, const float* __restrict__ w,
                        const float* __restrict__ wn, float* __restrict__ score){
  int row = blockIdx.x;
  float v = x[(size_t)row * HID + threadIdx.x] * w[threadIdx.x];
  v = waveReduceSum(v);
  __shared__ float sh[4];
  int lane = threadIdx.x & 63, wid = threadIdx.x >> 6;
  if (lane == 0) sh[wid] = v;
  __syncthreads();
  if (threadIdx.x == 0) score[row] = tanhf((sh[0] + sh[1] + sh[2] + sh[3]) / wn[0]);
}

// rank_i = #{j: s_j > s_i} + #{j<i: s_j == s_i}; perm[rank]=i for rank<k
// (matches jax.lax.top_k: descending, stable)
__global__ void k_topk(const float* __restrict__ score, int n, int k, int* __restrict__ perm){
  int i = blockIdx.x; float si = score[i];
  int cnt = 0;
  for (int j = threadIdx.x; j < n; j += 256){
    float sj = score[j];
    if (sj > si || (sj == si && j < i)) cnt++;
  }
#pragma unroll
  for (int off = 32; off > 0; off >>= 1) cnt += __shfl_down(cnt, off);
  __shared__ int sh[4];
  int lane = threadIdx.x & 63, wid = threadIdx.x >> 6;
  if (lane == 0) sh[wid] = cnt;
  __syncthreads();
  if (threadIdx.x == 0){
    int rank = sh[0] + sh[1] + sh[2] + sh[3];
    if (rank < k) perm[rank] = i;
  }
}

__global__ void k_pool_x(const float* __restrict__ x, const float* __restrict__ score,
                         const int* __restrict__ perm, float* __restrict__ xp, int C){
  int r = blockIdx.x; int pr = perm[r]; float s = score[pr];
  for (int c = threadIdx.x; c < C; c += 256)
    xp[(size_t)r * C + c] = x[(size_t)pr * C + c] * s;
}

// L[r][c] = A[perm[r]][c] + (perm[r]==c)
__global__ void k_gather_rows_plusI(const float* __restrict__ A, const int* __restrict__ perm,
                                    float* __restrict__ L, int n){
  int r = blockIdx.x; int pr = perm[r];
  for (int c = threadIdx.x; c < n; c += 256)
    L[(size_t)r * n + c] = A[(size_t)pr * n + c] + ((pr == c) ? 1.f : 0.f);
}

// R[k][s] = A[k][perm[s]] + (k==perm[s])
__global__ void k_gather_cols_plusI(const float* __restrict__ A, const int* __restrict__ perm,
                                    float* __restrict__ R, int n, int ncols){
  int k = blockIdx.x;
  for (int s = threadIdx.x; s < ncols; s += 256){
    int ps = perm[s];
    R[(size_t)k * ncols + s] = A[(size_t)k * n + ps] + ((k == ps) ? 1.f : 0.f);
  }
}

__global__ void k_zero_diag(float* __restrict__ A, int n){
  int i = blockIdx.x * blockDim.x + threadIdx.x;
  if (i < n) A[(size_t)i * n + i] = 0.f;
}

// buf[perm[i]][:] += xs[i][:]
__global__ void k_unpool_add(float* __restrict__ buf, const float* __restrict__ xs,
                             const int* __restrict__ perm, int C){
  int i = blockIdx.x; int p = perm[i];
  for (int c = threadIdx.x; c < C; c += 256)
    buf[(size_t)p * C + c] += xs[(size_t)i * C + c];
}

// ---------------- host orchestration ----------------
extern "C" void kernel_launch(void* const* d_in, const int* in_sizes, int n_in,
                              void* d_out, int out_size, void* d_ws, size_t ws_size,
                              hipStream_t stream){
  (void)in_sizes; (void)n_in; (void)out_size;
  const float* x_in = (const float*)d_in[0];
  const int*   ei   = (const int*)d_in[1];
  const float* dW0 = (const float*)d_in[2];
  const float* dW1 = (const float*)d_in[3];
  const float* dW2 = (const float*)d_in[4];
  const float* dW3 = (const float*)d_in[5];
  const float* db0 = (const float*)d_in[6];
  const float* db1 = (const float*)d_in[7];
  const float* db2 = (const float*)d_in[8];
  const float* db3 = (const float*)d_in[9];
  const float* pw0 = (const float*)d_in[10];
  const float* pw1 = (const float*)d_in[11];
  const float* pw2 = (const float*)d_in[12];
  const float* uW0 = (const float*)d_in[13];
  const float* uW1 = (const float*)d_in[14];
  const float* uW2 = (const float*)d_in[15];
  const float* ub0 = (const float*)d_in[16];
  const float* ub1 = (const float*)d_in[17];
  const float* ub2 = (const float*)d_in[18];

  char* p = (char*)d_ws;
  auto alloc = [&](size_t nbytes) -> void* {
    void* q = (void*)p; p += (nbytes + 255) & ~(size_t)255; return q;
  };
  float* A0 = (float*)alloc((size_t)NN * NN * 4);
  float* A1 = (float*)alloc((size_t)2048 * 2048 * 4);
  float* A2 = (float*)alloc((size_t)1024 * 1024 * 4);
  float* A3 = (float*)alloc((size_t)512 * 512 * 4);
  float* Rb = (float*)alloc((size_t)4096 * 2048 * 4);
  float* Lb = (float*)alloc((size_t)1024 * 2048 * 4);
  float* x0 = (float*)alloc((size_t)4096 * HID * 4);
  float* x1 = (float*)alloc((size_t)2048 * HID * 4);
  float* x2 = (float*)alloc((size_t)1024 * HID * 4);
  float* xc = (float*)alloc((size_t)2048 * HID * 4);
  float* xu = (float*)alloc((size_t)4096 * HID * 4);
  float* xv = (float*)alloc((size_t)2048 * HID * 4);
  float* Z  = (float*)alloc((size_t)4096 * HID * 4);
  float* Zs = (float*)alloc((size_t)4096 * HID * 4);
  float* Yb = (float*)alloc((size_t)4096 * HID * 4);
  float* dinv0 = (float*)alloc(4096 * 4);
  float* dinv1 = (float*)alloc(2048 * 4);
  float* dinv2 = (float*)alloc(1024 * 4);
  float* dinv3 = (float*)alloc(512 * 4);
  float* score = (float*)alloc(4096 * 4);
  float* wn    = (float*)alloc(256);
  int* perm1 = (int*)alloc(2048 * 4);
  int* perm2 = (int*)alloc(1024 * 4);
  int* perm3 = (int*)alloc(512 * 4);
  if ((size_t)(p - (char*)d_ws) > ws_size) return;  // insufficient workspace

  auto gemm = [&](const float* A, const float* B, float* C, int M, int N, int K){
    dim3 g(N / 64, M / 64);
    k_gemm<<<g, 256, 0, stream>>>(A, B, C, M, N, K);
  };
  // gcn_conv: out = act( dinv ⊙ ((A + 2I) @ (dinv ⊙ (x@W))) + b )
  auto conv_dense = [&](const float* xin, int n, int Cin, const float* W, int Cout,
                        const float* bias, const float* A, const float* dinv, int relu, float* out){
    gemm(xin, W, Z, n, Cout, Cin);
    k_scale_rows<<<n, 256, 0, stream>>>(Z, dinv, Zs, Cout);
    gemm(A, Zs, Yb, n, Cout, n);
    k_epilogue<<<n, 256, 0, stream>>>(Yb, Zs, dinv, bias, out, Cout, relu);
  };
  auto conv_sparse = [&](const float* xin, int n, int Cin, const float* W, int Cout,
                         const float* bias, const float* A, const float* dinv, int relu, float* out){
    gemm(xin, W, Z, n, Cout, Cin);
    k_scale_rows<<<n, 256, 0, stream>>>(Z, dinv, Zs, Cout);
    k_spmm<1><<<n, 256, 0, stream>>>(A, nullptr, 0, Zs, Yb, n, Cout);
    k_epilogue<<<n, 256, 0, stream>>>(Yb, Zs, dinv, bias, out, Cout, relu);
  };

  // ---- build A0, conv0 ----
  hipMemsetAsync(A0, 0, (size_t)NN * NN * 4, stream);
  k_build_A<<<EE / 256, 256, 0, stream>>>(ei, A0);
  k_dinv<<<NN, 256, 0, stream>>>(A0, dinv0, NN);
  conv_sparse(x_in, 4096, IN_DIM, dW0, HID, db0, A0, dinv0, 1, x0);

  // ---- pool 1 (4096 -> 2048) ----
  k_wnorm<<<1, 256, 0, stream>>>(pw0, wn);
  k_score<<<4096, 256, 0, stream>>>(x0, pw0, wn, score);
  k_topk<<<4096, 256, 0, stream>>>(score, 4096, 2048, perm1);
  // pooled augment: A1[r][s] = ((A0+I)@(A0+I))[perm1 r][perm1 s], diag zeroed
  k_gather_cols_plusI<<<4096, 256, 0, stream>>>(A0, perm1, Rb, 4096, 2048);
  k_spmm<8><<<2048, 256, 0, stream>>>(A0, perm1, 1, Rb, A1, 4096, 2048);
  k_zero_diag<<<8, 256, 0, stream>>>(A1, 2048);
  k_pool_x<<<2048, 256, 0, stream>>>(x0, score, perm1, xc, HID);
  k_dinv<<<2048, 256, 0, stream>>>(A1, dinv1, 2048);
  conv_dense(xc, 2048, HID, dW1, HID, db1, A1, dinv1, 1, x1);

  // ---- pool 2 (2048 -> 1024) ----
  k_wnorm<<<1, 256, 0, stream>>>(pw1, wn);
  k_score<<<2048, 256, 0, stream>>>(x1, pw1, wn, score);
  k_topk<<<2048, 256, 0, stream>>>(score, 2048, 1024, perm2);
  k_gather_rows_plusI<<<1024, 256, 0, stream>>>(A1, perm2, Lb, 2048);
  k_gather_cols_plusI<<<2048, 256, 0, stream>>>(A1, perm2, Rb, 2048, 1024);
  gemm(Lb, Rb, A2, 1024, 1024, 2048);
  k_zero_diag<<<4, 256, 0, stream>>>(A2, 1024);
  k_pool_x<<<1024, 256, 0, stream>>>(x1, score, perm2, xc, HID);
  k_dinv<<<1024, 256, 0, stream>>>(A2, dinv2, 1024);
  conv_dense(xc, 1024, HID, dW2, HID, db2, A2, dinv2, 1, x2);

  // ---- pool 3 (1024 -> 512) ----
  k_wnorm<<<1, 256, 0, stream>>>(pw2, wn);
  k_score<<<1024, 256, 0, stream>>>(x2, pw2, wn, score);
  k_topk<<<1024, 256, 0, stream>>>(score, 1024, 512, perm3);
  k_gather_rows_plusI<<<512, 256, 0, stream>>>(A2, perm3, Lb, 1024);
  k_gather_cols_plusI<<<1024, 256, 0, stream>>>(A2, perm3, Rb, 1024, 512);
  gemm(Lb, Rb, A3, 512, 512, 1024);
  k_zero_diag<<<2, 256, 0, stream>>>(A3, 512);
  k_pool_x<<<512, 256, 0, stream>>>(x2, score, perm3, xc, HID);
  k_dinv<<<512, 256, 0, stream>>>(A3, dinv3, 512);
  conv_dense(xc, 512, HID, dW3, HID, db3, A3, dinv3, 1, xv);   // xv = x3 (512x256)

  // ---- up 0 (j=2): res=x2(1024), perm3 ----
  hipMemcpyAsync(xu, x2, (size_t)1024 * HID * 4, hipMemcpyDeviceToDevice, stream);
  k_unpool_add<<<512, 256, 0, stream>>>(xu, xv, perm3, HID);
  conv_dense(xu, 1024, HID, uW0, HID, ub0, A2, dinv2, 1, xv);  // xv: 1024x256

  // ---- up 1 (j=1): res=x1(2048), perm2 ----
  hipMemcpyAsync(xu, x1, (size_t)2048 * HID * 4, hipMemcpyDeviceToDevice, stream);
  k_unpool_add<<<1024, 256, 0, stream>>>(xu, xv, perm2, HID);
  conv_dense(xu, 2048, HID, uW1, HID, ub1, A1, dinv1, 1, xv);  // xv: 2048x256

  // ---- up 2 (j=0): res=x0(4096), perm1, Cout=64, no relu, sparse A0 ----
  hipMemcpyAsync(xu, x0, (size_t)4096 * HID * 4, hipMemcpyDeviceToDevice, stream);
  k_unpool_add<<<2048, 256, 0, stream>>>(xu, xv, perm1, HID);
  gemm(xu, uW2, Z, 4096, OUT_DIM, HID);
  k_scale_rows<<<4096, 256, 0, stream>>>(Z, dinv0, Zs, OUT_DIM);
  k_spmm<1><<<4096, 256, 0, stream>>>(A0, nullptr, 0, Zs, Yb, 4096, OUT_DIM);
  k_epilogue<<<4096, 256, 0, stream>>>(Yb, Zs, dinv0, ub2, (float*)d_out, OUT_DIM, 0);
}

// Round 2
// 614.630 us; speedup vs baseline: 3.5179x; 3.5179x over previous
//
#include <hip/hip_runtime.h>
#include <math.h>

#define NN 4096
#define EE 131072
#define IN_DIM 512
#define HID 256
#define OUT_DIM 64

typedef unsigned short ushort_t;
typedef __attribute__((ext_vector_type(8))) short bf8_t;
typedef __attribute__((ext_vector_type(4))) float f4_t;

// ---------------- bf16 helpers (RNE) ----------------
__device__ __forceinline__ unsigned short f2bf(float v){
  union { float f; unsigned u; } x; x.f = v;
  unsigned r = x.u + 0x7fffu + ((x.u >> 16) & 1u);
  return (unsigned short)(r >> 16);
}
__device__ __forceinline__ float bf2f(unsigned short h){
  union { float f; unsigned u; } x; x.u = ((unsigned)h) << 16;
  return x.f;
}

__device__ __forceinline__ float waveReduceSum(float v){
#pragma unroll
  for (int off = 32; off > 0; off >>= 1) v += __shfl_down(v, off);
  return v;
}

// ---------------- graph build ----------------
__global__ void k_build_A(const int* __restrict__ ei, float* __restrict__ A){
  int e = blockIdx.x * blockDim.x + threadIdx.x;
  if (e < EE){
    int r = ei[e], c = ei[EE + e];
    A[(size_t)r * NN + c] = 1.0f;
  }
}

__global__ void k_dinv(const float* __restrict__ A, float* __restrict__ dinv, int n){
  int row = blockIdx.x;
  float s = 0.f;
  for (int j = threadIdx.x; j < n; j += 256) s += A[(size_t)row * n + j];
  s = waveReduceSum(s);
  __shared__ float sh[4];
  int lane = threadIdx.x & 63, wid = threadIdx.x >> 6;
  if (lane == 0) sh[wid] = s;
  __syncthreads();
  if (threadIdx.x == 0){
    float d = sh[0] + sh[1] + sh[2] + sh[3] + 2.0f;
    dinv[row] = (d > 0.f) ? (1.0f / sqrtf(d)) : 0.0f;
  }
}

template<int SRCL>
__global__ void k_dinv_bf(const unsigned short* __restrict__ Ah,
                          const unsigned short* __restrict__ Al,
                          float* __restrict__ dinv, int n){
  int row = blockIdx.x;
  float s = 0.f;
  for (int j = threadIdx.x; j < n; j += 256){
    float v = bf2f(Ah[(size_t)row * n + j]);
    if (SRCL) v += bf2f(Al[(size_t)row * n + j]);
    s += v;
  }
  s = waveReduceSum(s);
  __shared__ float sh[4];
  int lane = threadIdx.x & 63, wid = threadIdx.x >> 6;
  if (lane == 0) sh[wid] = s;
  __syncthreads();
  if (threadIdx.x == 0){
    float d = sh[0] + sh[1] + sh[2] + sh[3] + 2.0f;
    dinv[row] = (d > 0.f) ? (1.0f / sqrtf(d)) : 0.0f;
  }
}

// ---------------- MFMA GEMM ----------------
// C(MxN) = (Ah[+Al]) @ (Bh[+Bl])^T-layout; A row-major [M][K] bf16, B given as Bt [N][K] bf16.
// EPI 0: Cf=acc | 1: split acc -> Ch,Cl | 2: Cf=dinv[row]*acc | 3: Cf=relu?(dinv[row]*(acc+2Zs)+bias)
template<int HAS_AL, int HAS_BL, int HAS_LL, int EPI>
__global__ __launch_bounds__(256) void k_mm(
    const unsigned short* __restrict__ Ah, const unsigned short* __restrict__ Al,
    const unsigned short* __restrict__ Bh, const unsigned short* __restrict__ Bl,
    int M, int N, int K,
    float* __restrict__ Cf, unsigned short* __restrict__ Ch, unsigned short* __restrict__ Cl,
    const float* __restrict__ dinv, const float* __restrict__ Zs,
    const float* __restrict__ bias, int relu)
{
  __shared__ unsigned short lds[16384]; // 32KB: AH | AL | BH | BL (8KB each)
  char* LAH = (char*)lds;
  char* LAL = LAH + 8192;
  char* LBH = LAH + 16384;
  char* LBL = LAH + 24576;

  const int tid = threadIdx.x, lane = tid & 63, wid = tid >> 6;
  const int wm = wid >> 1, wn = wid & 1;
  const int bm = blockIdx.y << 6, bn = blockIdx.x << 6;
  const int l15 = lane & 15, l4 = lane >> 4;

  f4_t acc[2][2];
#pragma unroll
  for (int i = 0; i < 2; ++i)
#pragma unroll
    for (int j = 0; j < 2; ++j) acc[i][j] = (f4_t){0.f, 0.f, 0.f, 0.f};

  const size_t rb = (size_t)K * 2;
  const char* pAh = (const char*)Ah + (size_t)bm * rb;
  const char* pAl = HAS_AL ? (const char*)Al + (size_t)bm * rb : nullptr;
  const char* pBh = (const char*)Bh + (size_t)bn * rb;
  const char* pBl = HAS_BL ? (const char*)Bl + (size_t)bn * rb : nullptr;

  for (int k0 = 0; k0 < K; k0 += 64){
    __syncthreads();
    const size_t kbase = (size_t)k0 * 2;
#pragma unroll
    for (int it = 0; it < 2; ++it){
      const int c = tid + (it << 8);
      const int row = c >> 3, kc = (c & 7) << 4;
      const int off = row * 128 + (kc ^ ((row & 7) << 4));
      const size_t go = (size_t)row * rb + kbase + kc;
      *(int4*)(LAH + off) = *(const int4*)(pAh + go);
      if (HAS_AL) *(int4*)(LAL + off) = *(const int4*)(pAl + go);
      *(int4*)(LBH + off) = *(const int4*)(pBh + go);
      if (HAS_BL) *(int4*)(LBL + off) = *(const int4*)(pBl + go);
    }
    __syncthreads();
#pragma unroll
    for (int ks = 0; ks < 2; ++ks){
      bf8_t aH[2], aL[2], bH[2], bL[2];
#pragma unroll
      for (int f = 0; f < 2; ++f){
        int ar = wm * 32 + f * 16 + l15;
        int ao = ar * 128 + (((ks * 64) + (l4 << 4)) ^ ((ar & 7) << 4));
        aH[f] = *(const bf8_t*)(LAH + ao);
        if (HAS_AL) aL[f] = *(const bf8_t*)(LAL + ao);
        int br = wn * 32 + f * 16 + l15;
        int bo = br * 128 + (((ks * 64) + (l4 << 4)) ^ ((br & 7) << 4));
        bH[f] = *(const bf8_t*)(LBH + bo);
        if (HAS_BL) bL[f] = *(const bf8_t*)(LBL + bo);
      }
#pragma unroll
      for (int i = 0; i < 2; ++i)
#pragma unroll
        for (int j = 0; j < 2; ++j){
          acc[i][j] = __builtin_amdgcn_mfma_f32_16x16x32_bf16(aH[i], bH[j], acc[i][j], 0, 0, 0);
          if (HAS_BL) acc[i][j] = __builtin_amdgcn_mfma_f32_16x16x32_bf16(aH[i], bL[j], acc[i][j], 0, 0, 0);
          if (HAS_AL) acc[i][j] = __builtin_amdgcn_mfma_f32_16x16x32_bf16(aL[i], bH[j], acc[i][j], 0, 0, 0);
          if (HAS_LL) acc[i][j] = __builtin_amdgcn_mfma_f32_16x16x32_bf16(aL[i], bL[j], acc[i][j], 0, 0, 0);
        }
    }
  }

  // epilogue: C[row][col], row = (l>>4)*4 + r, col = l&15 within each 16x16 frag
#pragma unroll
  for (int i = 0; i < 2; ++i)
#pragma unroll
    for (int j = 0; j < 2; ++j)
#pragma unroll
      for (int r = 0; r < 4; ++r){
        int grow = bm + wm * 32 + i * 16 + l4 * 4 + r;
        int gcol = bn + wn * 32 + j * 16 + l15;
        float v = acc[i][j][r];
        size_t o = (size_t)grow * N + gcol;
        if (EPI == 0){
          Cf[o] = v;
        } else if (EPI == 1){
          unsigned short h = f2bf(v);
          Ch[o] = h; Cl[o] = f2bf(v - bf2f(h));
        } else if (EPI == 2){
          Cf[o] = dinv[grow] * v;
        } else {
          float out = dinv[grow] * (v + 2.0f * Zs[o]) + bias[gcol];
          if (relu) out = fmaxf(out, 0.f);
          Cf[o] = out;
        }
      }
}

// ---------------- sparse-row x dense (A0-based ops) ----------------
#define SP_CAP 1024
template<int CPT, int OUTBF>
__global__ __launch_bounds__(256) void k_spmm(const float* __restrict__ S,
                                              const int* __restrict__ rowperm, int plusI,
                                              const float* __restrict__ D,
                                              float* __restrict__ Cf,
                                              unsigned short* __restrict__ Cb,
                                              int K, int Ncols){
  int r = blockIdx.x;
  int srow = rowperm ? rowperm[r] : r;
  __shared__ int   s_idx[SP_CAP];
  __shared__ float s_val[SP_CAP];
  __shared__ int   s_cnt[256];
  const float* Srow = S + (size_t)srow * K;
  int cnt = 0;
  for (int k = threadIdx.x; k < K; k += 256) if (Srow[k] != 0.f) cnt++;
  s_cnt[threadIdx.x] = cnt;
  __syncthreads();
  for (int off = 1; off < 256; off <<= 1){
    int a = s_cnt[threadIdx.x];
    int b = (threadIdx.x >= off) ? s_cnt[threadIdx.x - off] : 0;
    __syncthreads();
    s_cnt[threadIdx.x] = a + b;
    __syncthreads();
  }
  int total = s_cnt[255];
  int pos = s_cnt[threadIdx.x] - cnt;
  for (int k = threadIdx.x; k < K; k += 256){
    float v = Srow[k];
    if (v != 0.f){ if (pos < SP_CAP){ s_idx[pos] = k; s_val[pos] = v; } pos++; }
  }
  if (plusI && threadIdx.x == 0 && total < SP_CAP){ s_idx[total] = srow; s_val[total] = 1.0f; }
  __syncthreads();
  int n_nz = total + (plusI ? 1 : 0); if (n_nz > SP_CAP) n_nz = SP_CAP;
  float acc[CPT];
#pragma unroll
  for (int j = 0; j < CPT; ++j) acc[j] = 0.f;
  for (int e = 0; e < n_nz; ++e){
    int k = s_idx[e]; float v = s_val[e];
    const float* Drow = D + (size_t)k * Ncols;
#pragma unroll
    for (int j = 0; j < CPT; ++j){
      int c = threadIdx.x + (j << 8);
      if (c < Ncols) acc[j] += v * Drow[c];
    }
  }
#pragma unroll
  for (int j = 0; j < CPT; ++j){
    int c = threadIdx.x + (j << 8);
    if (c < Ncols){
      if (OUTBF) Cb[(size_t)r * Ncols + c] = f2bf(acc[j]);
      else       Cf[(size_t)r * Ncols + c] = acc[j];
    }
  }
}

// ---------------- elementwise / epilogue helpers ----------------
__global__ void k_epilogue(const float* __restrict__ Y, const float* __restrict__ Zs,
                           const float* __restrict__ dinv, const float* __restrict__ b,
                           float* __restrict__ out, int C, int relu){
  int row = blockIdx.x; float di = dinv[row];
  for (int c = threadIdx.x; c < C; c += 256){
    float v = di * (Y[(size_t)row * C + c] + 2.0f * Zs[(size_t)row * C + c]) + b[c];
    out[(size_t)row * C + c] = relu ? fmaxf(v, 0.f) : v;
  }
}

__global__ void k_split(const float* __restrict__ X, unsigned short* __restrict__ H,
                        unsigned short* __restrict__ L, int n){
  int i = blockIdx.x * 256 + threadIdx.x;
  if (i < n){
    float v = X[i];
    unsigned short h = f2bf(v);
    H[i] = h; L[i] = f2bf(v - bf2f(h));
  }
}

// transpose + split: X[R][C] fp32 -> Th,Tl [C][R] bf16 (R,C multiples of 32)
__global__ __launch_bounds__(256) void k_tsplit(const float* __restrict__ X, int R, int C,
                                                unsigned short* __restrict__ Th,
                                                unsigned short* __restrict__ Tl){
  __shared__ float t[32][33];
  int bx = blockIdx.x * 32;  // col tile
  int by = blockIdx.y * 32;  // row tile
  int tx = threadIdx.x & 31, ty = threadIdx.x >> 5;
#pragma unroll
  for (int i = 0; i < 4; ++i)
    t[ty + i * 8][tx] = X[(size_t)(by + ty + i * 8) * C + bx + tx];
  __syncthreads();
#pragma unroll
  for (int i = 0; i < 4; ++i){
    float v = t[tx][ty + i * 8];
    unsigned short h = f2bf(v);
    size_t o = (size_t)(bx + ty + i * 8) * R + by + tx;
    Th[o] = h; Tl[o] = f2bf(v - bf2f(h));
  }
}

__global__ void k_wnorm(const float* __restrict__ w, float* __restrict__ out){
  float v = w[threadIdx.x]; v *= v;
  v = waveReduceSum(v);
  __shared__ float sh[4];
  int lane = threadIdx.x & 63, wid = threadIdx.x >> 6;
  if (lane == 0) sh[wid] = v;
  __syncthreads();
  if (threadIdx.x == 0) out[0] = sqrtf(sh[0] + sh[1] + sh[2] + sh[3]);
}

__global__ void k_score(const float* __restrict__ x, const float* __restrict__ w,
                        const float* __restrict__ wn, float* __restrict__ score){
  int row = blockIdx.x;
  float v = x[(size_t)row * HID + threadIdx.x] * w[threadIdx.x];
  v = waveReduceSum(v);
  __shared__ float sh[4];
  int lane = threadIdx.x & 63, wid = threadIdx.x >> 6;
  if (lane == 0) sh[wid] = v;
  __syncthreads();
  if (threadIdx.x == 0) score[row] = tanhf((sh[0] + sh[1] + sh[2] + sh[3]) / wn[0]);
}

__global__ void k_topk(const float* __restrict__ score, int n, int k, int* __restrict__ perm){
  int i = blockIdx.x; float si = score[i];
  int cnt = 0;
  for (int j = threadIdx.x; j < n; j += 256){
    float sj = score[j];
    if (sj > si || (sj == si && j < i)) cnt++;
  }
#pragma unroll
  for (int off = 32; off > 0; off >>= 1) cnt += __shfl_down(cnt, off);
  __shared__ int sh[4];
  int lane = threadIdx.x & 63, wid = threadIdx.x >> 6;
  if (lane == 0) sh[wid] = cnt;
  __syncthreads();
  if (threadIdx.x == 0){
    int rank = sh[0] + sh[1] + sh[2] + sh[3];
    if (rank < k) perm[rank] = i;
  }
}

// xp (gated, pooled) written directly as bf16 hi/lo (feeds GEMM1 A-operand only)
__global__ void k_pool_x2(const float* __restrict__ x, const float* __restrict__ score,
                          const int* __restrict__ perm,
                          unsigned short* __restrict__ xh, unsigned short* __restrict__ xl, int C){
  int r = blockIdx.x; int pr = perm[r]; float s = score[pr];
  for (int c = threadIdx.x; c < C; c += 256){
    float v = x[(size_t)pr * C + c] * s;
    unsigned short h = f2bf(v);
    xh[(size_t)r * C + c] = h;
    xl[(size_t)r * C + c] = f2bf(v - bf2f(h));
  }
}

// fp32 gather of A0 columns (+I) for the level-1 sparse squaring
__global__ void k_gather_cols_plusI(const float* __restrict__ A, const int* __restrict__ perm,
                                    float* __restrict__ R, int n, int ncols){
  int k = blockIdx.x;
  for (int s = threadIdx.x; s < ncols; s += 256){
    int ps = perm[s];
    R[(size_t)k * ncols + s] = A[(size_t)k * n + ps] + ((k == ps) ? 1.f : 0.f);
  }
}

// bf16 row gather (+I): D[r][c] = (Sh+Sl)[perm[r]][c] + (perm[r]==c), resplit
template<int SRCL, int OUTL>
__global__ void k_grow_b(const unsigned short* __restrict__ Sh, const unsigned short* __restrict__ Sl,
                         const int* __restrict__ perm,
                         unsigned short* __restrict__ Dh, unsigned short* __restrict__ Dl, int n){
  int r = blockIdx.x, pr = perm[r];
  for (int c = threadIdx.x; c < n; c += 256){
    float v = bf2f(Sh[(size_t)pr * n + c]);
    if (SRCL) v += bf2f(Sl[(size_t)pr * n + c]);
    if (pr == c) v += 1.f;
    unsigned short h = f2bf(v);
    Dh[(size_t)r * n + c] = h;
    if (OUTL) Dl[(size_t)r * n + c] = f2bf(v - bf2f(h));
  }
}

// bf16 col gather, transposed out (+I): D[s][k] = (Sh+Sl)[k][perm[s]] + (k==perm[s])
template<int SRCL, int OUTL>
__global__ void k_gcolT_b(const unsigned short* __restrict__ Sh, const unsigned short* __restrict__ Sl,
                          const int* __restrict__ perm,
                          unsigned short* __restrict__ Dh, unsigned short* __restrict__ Dl, int n){
  int s = blockIdx.x, ps = perm[s];
  for (int k = threadIdx.x; k < n; k += 256){
    float v = bf2f(Sh[(size_t)k * n + ps]);
    if (SRCL) v += bf2f(Sl[(size_t)k * n + ps]);
    if (k == ps) v += 1.f;
    unsigned short h = f2bf(v);
    Dh[(size_t)s * n + k] = h;
    if (OUTL) Dl[(size_t)s * n + k] = f2bf(v - bf2f(h));
  }
}

__global__ void k_zdiag_b(unsigned short* __restrict__ H, unsigned short* __restrict__ L, int n){
  int i = blockIdx.x * blockDim.x + threadIdx.x;
  if (i < n){ H[(size_t)i * n + i] = 0; if (L) L[(size_t)i * n + i] = 0; }
}

__global__ void k_unpool_add(float* __restrict__ buf, const float* __restrict__ xs,
                             const int* __restrict__ perm, int C){
  int i = blockIdx.x; int p = perm[i];
  for (int c = threadIdx.x; c < C; c += 256)
    buf[(size_t)p * C + c] += xs[(size_t)i * C + c];
}

// ---------------- host orchestration ----------------
extern "C" void kernel_launch(void* const* d_in, const int* in_sizes, int n_in,
                              void* d_out, int out_size, void* d_ws, size_t ws_size,
                              hipStream_t stream){
  (void)in_sizes; (void)n_in; (void)out_size;
  const float* x_in = (const float*)d_in[0];
  const int*   ei   = (const int*)d_in[1];
  const float* dW0 = (const float*)d_in[2];
  const float* dW1 = (const float*)d_in[3];
  const float* dW2 = (const float*)d_in[4];
  const float* dW3 = (const float*)d_in[5];
  const float* db0 = (const float*)d_in[6];
  const float* db1 = (const float*)d_in[7];
  const float* db2 = (const float*)d_in[8];
  const float* db3 = (const float*)d_in[9];
  const float* pw0 = (const float*)d_in[10];
  const float* pw1 = (const float*)d_in[11];
  const float* pw2 = (const float*)d_in[12];
  const float* uW0 = (const float*)d_in[13];
  const float* uW1 = (const float*)d_in[14];
  const float* uW2 = (const float*)d_in[15];
  const float* ub0 = (const float*)d_in[16];
  const float* ub1 = (const float*)d_in[17];
  const float* ub2 = (const float*)d_in[18];

  char* p = (char*)d_ws;
  auto alloc = [&](size_t nbytes) -> void* {
    void* q = (void*)p; p += (nbytes + 255) & ~(size_t)255; return q;
  };
  float* A0   = (float*)alloc((size_t)NN * NN * 4);          // 64M, persistent
  char*  RB   = (char*)alloc((size_t)4096 * 2048 * 4);       // 32M multi-use arena
  unsigned short* A1h = (unsigned short*)alloc((size_t)2048 * 2048 * 2);
  unsigned short* A2h = (unsigned short*)alloc((size_t)1024 * 1024 * 2);
  unsigned short* A2l = (unsigned short*)alloc((size_t)1024 * 1024 * 2);
  unsigned short* A3h = (unsigned short*)alloc((size_t)512 * 512 * 2);
  unsigned short* A3l = (unsigned short*)alloc((size_t)512 * 512 * 2);
  float* x0 = (float*)alloc((size_t)4096 * HID * 4);
  float* x1 = (float*)alloc((size_t)2048 * HID * 4);
  float* x2 = (float*)alloc((size_t)1024 * HID * 4);
  float* xv = (float*)alloc((size_t)2048 * HID * 4);
  float* xu = (float*)alloc((size_t)4096 * HID * 4);
  unsigned short* xuh = (unsigned short*)alloc((size_t)4096 * HID * 2);
  unsigned short* xul = (unsigned short*)alloc((size_t)4096 * HID * 2);
  unsigned short* xph = (unsigned short*)alloc((size_t)2048 * HID * 2);
  unsigned short* xpl = (unsigned short*)alloc((size_t)2048 * HID * 2);
  unsigned short* Wth = (unsigned short*)alloc((size_t)512 * 256 * 2);
  unsigned short* Wtl = (unsigned short*)alloc((size_t)512 * 256 * 2);
  float* Zs  = (float*)alloc((size_t)4096 * HID * 4);
  unsigned short* ZsTh = (unsigned short*)alloc((size_t)256 * 2048 * 2);
  unsigned short* ZsTl = (unsigned short*)alloc((size_t)256 * 2048 * 2);
  float* Yb = (float*)alloc((size_t)4096 * HID * 4);
  float* dinv0 = (float*)alloc(4096 * 4);
  float* dinv1 = (float*)alloc(2048 * 4);
  float* dinv2 = (float*)alloc(1024 * 4);
  float* dinv3 = (float*)alloc(512 * 4);
  float* score = (float*)alloc(4096 * 4);
  float* wn    = (float*)alloc(256);
  int* perm1 = (int*)alloc(2048 * 4);
  int* perm2 = (int*)alloc(1024 * 4);
  int* perm3 = (int*)alloc(512 * 4);
  if ((size_t)(p - (char*)d_ws) > ws_size) return;

  // RB arena sub-allocations (time-disjoint):
  unsigned short* xinh = (unsigned short*)(RB);                         // phase A (conv0)
  unsigned short* xinl = (unsigned short*)(RB + (size_t)4 * 1024 * 1024);
  float* Rb = (float*)RB;                                               // phase B (pool1)
  unsigned short* Lb2h = (unsigned short*)(RB);                         // phase C (pool2)
  unsigned short* Rt2h = (unsigned short*)(RB + (size_t)4 * 1024 * 1024);
  unsigned short* Lb3h = (unsigned short*)(RB + (size_t)8 * 1024 * 1024);   // phase D (pool3)
  unsigned short* Lb3l = (unsigned short*)(RB + (size_t)9 * 1024 * 1024);
  unsigned short* Rt3h = (unsigned short*)(RB + (size_t)10 * 1024 * 1024);
  unsigned short* Rt3l = (unsigned short*)(RB + (size_t)11 * 1024 * 1024);

  auto tsplit = [&](const float* X, int R, int C, unsigned short* Th, unsigned short* Tl){
    dim3 g(C / 32, R / 32);
    k_tsplit<<<g, 256, 0, stream>>>(X, R, C, Th, Tl);
  };

  // ================= build A0, level-0 conv (sparse) =================
  hipMemsetAsync(A0, 0, (size_t)NN * NN * 4, stream);
  k_build_A<<<EE / 256, 256, 0, stream>>>(ei, A0);
  k_dinv<<<NN, 256, 0, stream>>>(A0, dinv0, NN);
  k_split<<<(4096 * 512 + 255) / 256, 256, 0, stream>>>(x_in, xinh, xinl, 4096 * 512);
  tsplit(dW0, IN_DIM, HID, Wth, Wtl);
  { dim3 g(HID / 64, 4096 / 64);
    k_mm<1,1,0,2><<<g, 256, 0, stream>>>(xinh, xinl, Wth, Wtl, 4096, HID, IN_DIM,
                                         Zs, nullptr, nullptr, dinv0, nullptr, nullptr, 0); }
  k_spmm<1,0><<<4096, 256, 0, stream>>>(A0, nullptr, 0, Zs, Yb, nullptr, 4096, HID);
  k_epilogue<<<4096, 256, 0, stream>>>(Yb, Zs, dinv0, db0, x0, HID, 1);

  // ================= pool 1 (4096 -> 2048) =================
  k_wnorm<<<1, 256, 0, stream>>>(pw0, wn);
  k_score<<<4096, 256, 0, stream>>>(x0, pw0, wn, score);
  k_topk<<<4096, 256, 0, stream>>>(score, 4096, 2048, perm1);
  k_gather_cols_plusI<<<4096, 256, 0, stream>>>(A0, perm1, Rb, 4096, 2048);
  k_spmm<8,1><<<2048, 256, 0, stream>>>(A0, perm1, 1, Rb, nullptr, A1h, 4096, 2048);
  k_zdiag_b<<<8, 256, 0, stream>>>(A1h, nullptr, 2048);
  k_pool_x2<<<2048, 256, 0, stream>>>(x0, score, perm1, xph, xpl, HID);
  k_dinv_bf<0><<<2048, 256, 0, stream>>>(A1h, nullptr, dinv1, 2048);
  // conv1: GEMM1 + tsplit + GEMM2(A1h, B split)
  tsplit(dW1, HID, HID, Wth, Wtl);
  { dim3 g(HID / 64, 2048 / 64);
    k_mm<1,1,0,2><<<g, 256, 0, stream>>>(xph, xpl, Wth, Wtl, 2048, HID, HID,
                                         Zs, nullptr, nullptr, dinv1, nullptr, nullptr, 0); }
  tsplit(Zs, 2048, HID, ZsTh, ZsTl);
  { dim3 g(HID / 64, 2048 / 64);
    k_mm<0,1,0,3><<<g, 256, 0, stream>>>(A1h, nullptr, ZsTh, ZsTl, 2048, HID, 2048,
                                         x1, nullptr, nullptr, dinv1, Zs, db1, 1); }

  // ================= pool 2 (2048 -> 1024) =================
  k_wnorm<<<1, 256, 0, stream>>>(pw1, wn);
  k_score<<<2048, 256, 0, stream>>>(x1, pw1, wn, score);
  k_topk<<<2048, 256, 0, stream>>>(score, 2048, 1024, perm2);
  k_grow_b<0,0><<<1024, 256, 0, stream>>>(A1h, nullptr, perm2, Lb2h, nullptr, 2048);
  k_gcolT_b<0,0><<<1024, 256, 0, stream>>>(A1h, nullptr, perm2, Rt2h, nullptr, 2048);
  { dim3 g(1024 / 64, 1024 / 64);
    k_mm<0,0,0,1><<<g, 256, 0, stream>>>(Lb2h, nullptr, Rt2h, nullptr, 1024, 1024, 2048,
                                         nullptr, A2h, A2l, nullptr, nullptr, nullptr, 0); }
  k_zdiag_b<<<4, 256, 0, stream>>>(A2h, A2l, 1024);
  k_pool_x2<<<1024, 256, 0, stream>>>(x1, score, perm2, xph, xpl, HID);
  k_dinv_bf<1><<<1024, 256, 0, stream>>>(A2h, A2l, dinv2, 1024);
  tsplit(dW2, HID, HID, Wth, Wtl);
  { dim3 g(HID / 64, 1024 / 64);
    k_mm<1,1,0,2><<<g, 256, 0, stream>>>(xph, xpl, Wth, Wtl, 1024, HID, HID,
                                         Zs, nullptr, nullptr, dinv2, nullptr, nullptr, 0); }
  tsplit(Zs, 1024, HID, ZsTh, ZsTl);
  { dim3 g(HID / 64, 1024 / 64);
    k_mm<1,1,0,3><<<g, 256, 0, stream>>>(A2h, A2l, ZsTh, ZsTl, 1024, HID, 1024,
                                         x2, nullptr, nullptr, dinv2, Zs, db2, 1); }

  // ================= pool 3 (1024 -> 512) =================
  k_wnorm<<<1, 256, 0, stream>>>(pw2, wn);
  k_score<<<1024, 256, 0, stream>>>(x2, pw2, wn, score);
  k_topk<<<1024, 256, 0, stream>>>(score, 1024, 512, perm3);
  k_grow_b<1,1><<<512, 256, 0, stream>>>(A2h, A2l, perm3, Lb3h, Lb3l, 1024);
  k_gcolT_b<1,1><<<512, 256, 0, stream>>>(A2h, A2l, perm3, Rt3h, Rt3l, 1024);
  { dim3 g(512 / 64, 512 / 64);
    k_mm<1,1,1,1><<<g, 256, 0, stream>>>(Lb3h, Lb3l, Rt3h, Rt3l, 512, 512, 1024,
                                         nullptr, A3h, A3l, nullptr, nullptr, nullptr, 0); }
  k_zdiag_b<<<2, 256, 0, stream>>>(A3h, A3l, 512);
  k_pool_x2<<<512, 256, 0, stream>>>(x2, score, perm3, xph, xpl, HID);
  k_dinv_bf<1><<<512, 256, 0, stream>>>(A3h, A3l, dinv3, 512);
  tsplit(dW3, HID, HID, Wth, Wtl);
  { dim3 g(HID / 64, 512 / 64);
    k_mm<1,1,0,2><<<g, 256, 0, stream>>>(xph, xpl, Wth, Wtl, 512, HID, HID,
                                         Zs, nullptr, nullptr, dinv3, nullptr, nullptr, 0); }
  tsplit(Zs, 512, HID, ZsTh, ZsTl);
  { dim3 g(HID / 64, 512 / 64);
    k_mm<1,1,0,3><<<g, 256, 0, stream>>>(A3h, A3l, ZsTh, ZsTl, 512, HID, 512,
                                         xv, nullptr, nullptr, dinv3, Zs, db3, 1); }  // xv = x3

  // ================= up 0 (res=x2, perm3, A2) =================
  hipMemcpyAsync(xu, x2, (size_t)1024 * HID * 4, hipMemcpyDeviceToDevice, stream);
  k_unpool_add<<<512, 256, 0, stream>>>(xu, xv, perm3, HID);
  k_split<<<(1024 * HID + 255) / 256, 256, 0, stream>>>(xu, xuh, xul, 1024 * HID);
  tsplit(uW0, HID, HID, Wth, Wtl);
  { dim3 g(HID / 64, 1024 / 64);
    k_mm<1,1,0,2><<<g, 256, 0, stream>>>(xuh, xul, Wth, Wtl, 1024, HID, HID,
                                         Zs, nullptr, nullptr, dinv2, nullptr, nullptr, 0); }
  tsplit(Zs, 1024, HID, ZsTh, ZsTl);
  { dim3 g(HID / 64, 1024 / 64);
    k_mm<1,1,0,3><<<g, 256, 0, stream>>>(A2h, A2l, ZsTh, ZsTl, 1024, HID, 1024,
                                         xv, nullptr, nullptr, dinv2, Zs, ub0, 1); }

  // ================= up 1 (res=x1, perm2, A1) =================
  hipMemcpyAsync(xu, x1, (size_t)2048 * HID * 4, hipMemcpyDeviceToDevice, stream);
  k_unpool_add<<<1024, 256, 0, stream>>>(xu, xv, perm2, HID);
  k_split<<<(2048 * HID + 255) / 256, 256, 0, stream>>>(xu, xuh, xul, 2048 * HID);
  tsplit(uW1, HID, HID, Wth, Wtl);
  { dim3 g(HID / 64, 2048 / 64);
    k_mm<1,1,0,2><<<g, 256, 0, stream>>>(xuh, xul, Wth, Wtl, 2048, HID, HID,
                                         Zs, nullptr, nullptr, dinv1, nullptr, nullptr, 0); }
  tsplit(Zs, 2048, HID, ZsTh, ZsTl);
  { dim3 g(HID / 64, 2048 / 64);
    k_mm<0,1,0,3><<<g, 256, 0, stream>>>(A1h, nullptr, ZsTh, ZsTl, 2048, HID, 2048,
                                         xv, nullptr, nullptr, dinv1, Zs, ub1, 1); }

  // ================= up 2 (res=x0, perm1, A0 sparse, Cout=64, no relu) =================
  hipMemcpyAsync(xu, x0, (size_t)4096 * HID * 4, hipMemcpyDeviceToDevice, stream);
  k_unpool_add<<<2048, 256, 0, stream>>>(xu, xv, perm1, HID);
  k_split<<<(4096 * HID + 255) / 256, 256, 0, stream>>>(xu, xuh, xul, 4096 * HID);
  tsplit(uW2, HID, OUT_DIM, Wth, Wtl);
  { dim3 g(OUT_DIM / 64, 4096 / 64);
    k_mm<1,1,0,2><<<g, 256, 0, stream>>>(xuh, xul, Wth, Wtl, 4096, OUT_DIM, HID,
                                         Zs, nullptr, nullptr, dinv0, nullptr, nullptr, 0); }
  k_spmm<1,0><<<4096, 256, 0, stream>>>(A0, nullptr, 0, Zs, Yb, nullptr, 4096, OUT_DIM);
  k_epilogue<<<4096, 256, 0, stream>>>(Yb, Zs, dinv0, ub2, (float*)d_out, OUT_DIM, 0);
}

// Round 3
// 392.742 us; speedup vs baseline: 5.5054x; 1.5650x over previous
//
#include <hip/hip_runtime.h>
#include <math.h>

#define NN 4096
#define EE 131072
#define IN_DIM 512
#define HID 256
#define OUT_DIM 64
#define ECAP 128

typedef __attribute__((ext_vector_type(8))) short bf8_t;
typedef __attribute__((ext_vector_type(4))) float f4_t;
typedef __attribute__((ext_vector_type(8))) unsigned short us8_t;

// ---------------- bf16 helpers (RNE) ----------------
__device__ __forceinline__ unsigned short f2bf(float v){
  union { float f; unsigned u; } x; x.f = v;
  unsigned r = x.u + 0x7fffu + ((x.u >> 16) & 1u);
  return (unsigned short)(r >> 16);
}
__device__ __forceinline__ float bf2f(unsigned short h){
  union { float f; unsigned u; } x; x.u = ((unsigned)h) << 16;
  return x.f;
}

__device__ __forceinline__ float waveReduceSum(float v){
#pragma unroll
  for (int off = 32; off > 0; off >>= 1) v += __shfl_down(v, off);
  return v;
}

// ---------------- graph build: bitmask + ELL ----------------
__global__ void k_build_bits(const int* __restrict__ ei, unsigned* __restrict__ bits){
  int e = blockIdx.x * blockDim.x + threadIdx.x;
  if (e < EE){
    int r = ei[e], c = ei[EE + e];
    atomicOr(&bits[r * 128 + (c >> 5)], 1u << (c & 31));
  }
}

__global__ __launch_bounds__(128) void k_ell(const unsigned* __restrict__ bits,
                                             int* __restrict__ ell, int* __restrict__ cnt,
                                             float* __restrict__ dinv){
  int r = blockIdx.x, t = threadIdx.x;
  unsigned w = bits[r * 128 + t];
  int c = __popc(w);
  __shared__ int sc[128];
  sc[t] = c; __syncthreads();
  for (int off = 1; off < 128; off <<= 1){
    int a = sc[t], b = (t >= off) ? sc[t - off] : 0;
    __syncthreads(); sc[t] = a + b; __syncthreads();
  }
  int total = sc[127];
  int pos = sc[t] - c;
  int base = r * ECAP;
  while (w){
    int b = __ffs(w) - 1; w &= w - 1;
    if (pos < ECAP) ell[base + pos] = t * 32 + b;
    pos++;
  }
  if (t == 0){
    cnt[r] = (total < ECAP) ? total : ECAP;
    dinv[r] = 1.0f / sqrtf((float)total + 2.0f);
  }
}

// ---------------- fused SpMM (ELL, values==1) + GCN epilogue ----------------
// out[r][:] = act( dinv[r]*(sum_{k in ell[r]} Zs[k][:] + 2*Zs[r][:]) + bias )
template<int NCOLS, int RELU>
__global__ __launch_bounds__(256) void k_spmm_ell(
    const int* __restrict__ ell, const int* __restrict__ cnt,
    const float* __restrict__ Zs, const float* __restrict__ dinv,
    const float* __restrict__ bias, float* __restrict__ out)
{
  int r = blockIdx.x;
  __shared__ int s_idx[ECAP];
  __shared__ int s_n;
  __shared__ float sh[4 * NCOLS];
  if (threadIdx.x == 0) s_n = cnt[r];
  for (int i = threadIdx.x; i < ECAP; i += 256) s_idx[i] = ell[r * ECAP + i];
  __syncthreads();
  int n = s_n; if (n > ECAP) n = ECAP;
  int w = threadIdx.x >> 6, lane = threadIdx.x & 63;
  if (NCOLS == 256){
    f4_t acc = (f4_t){0.f, 0.f, 0.f, 0.f};
    for (int e = w; e < n; e += 4){
      const f4_t* row = (const f4_t*)(Zs + (size_t)s_idx[e] * 256);
      acc += row[lane];
    }
    ((f4_t*)(sh + w * 256))[lane] = acc;
  } else { // NCOLS == 64
    float acc = 0.f;
    for (int e = w; e < n; e += 4)
      acc += Zs[(size_t)s_idx[e] * 64 + lane];
    sh[w * 64 + lane] = acc;
  }
  __syncthreads();
  int t = threadIdx.x;
  if (t < NCOLS){
    float y = sh[t] + sh[NCOLS + t] + sh[2 * NCOLS + t] + sh[3 * NCOLS + t];
    float z = Zs[(size_t)r * NCOLS + t];
    float o = dinv[r] * (y + 2.0f * z) + bias[t];
    out[(size_t)r * NCOLS + t] = RELU ? fmaxf(o, 0.f) : o;
  }
}

// ---------------- pool-1 squaring from ELL ----------------
__global__ void k_invsel_init(int* __restrict__ inv, int n){
  int i = blockIdx.x * 256 + threadIdx.x; if (i < n) inv[i] = -1;
}
__global__ void k_invsel_set(const int* __restrict__ perm, int* __restrict__ inv, int n){
  int i = blockIdx.x * 256 + threadIdx.x; if (i < n) inv[perm[i]] = i;
}

// Rb[k][s] = (A0+I)[k][perm1[s]]  as bf16 (values 0/1/2 exact)
__global__ __launch_bounds__(256) void k_build_Rb(const int* __restrict__ ell, const int* __restrict__ cnt,
                                                  const int* __restrict__ invsel,
                                                  unsigned short* __restrict__ Rb){
  int k = blockIdx.x;
  __shared__ unsigned short row[2048];
  for (int i = threadIdx.x; i < 2048; i += 256) row[i] = 0;
  __syncthreads();
  int n = cnt[k];
  for (int e = threadIdx.x; e < n; e += 256){
    int s = invsel[ell[k * ECAP + e]];
    if (s >= 0) row[s] = 0x3F80;  // 1.0
  }
  __syncthreads();
  if (threadIdx.x == 0){
    int sk = invsel[k];
    if (sk >= 0) row[sk] = (row[sk] == 0x3F80) ? 0x4000 : 0x3F80; // +1 -> 2.0 or 1.0
  }
  __syncthreads();
  for (int i = threadIdx.x; i < 2048; i += 256)
    Rb[(size_t)k * 2048 + i] = row[i];
}

// A1h[r][:] = Rb[pr][:] + sum_{k in ell[pr]} Rb[k][:]   (integers < 256, exact bf16)
__global__ __launch_bounds__(256) void k_sq1(const int* __restrict__ ell, const int* __restrict__ cnt,
                                             const int* __restrict__ perm,
                                             const unsigned short* __restrict__ Rb,
                                             unsigned short* __restrict__ A1h){
  int r = blockIdx.x;
  int pr = perm[r];
  __shared__ int s_idx[ECAP];
  __shared__ int s_n;
  if (threadIdx.x == 0) s_n = cnt[pr];
  for (int i = threadIdx.x; i < ECAP; i += 256) s_idx[i] = ell[pr * ECAP + i];
  __syncthreads();
  int n = s_n; if (n > ECAP) n = ECAP;
  int colb = (threadIdx.x >> 6) * 512 + (threadIdx.x & 63) * 8;
  float acc[8];
  { us8_t v = *(const us8_t*)(Rb + (size_t)pr * 2048 + colb);
#pragma unroll
    for (int j = 0; j < 8; ++j) acc[j] = bf2f(v[j]); }
  for (int e = 0; e < n; ++e){
    int k = s_idx[e];
    us8_t v = *(const us8_t*)(Rb + (size_t)k * 2048 + colb);
#pragma unroll
    for (int j = 0; j < 8; ++j) acc[j] += bf2f(v[j]);
  }
  us8_t o;
#pragma unroll
  for (int j = 0; j < 8; ++j) o[j] = f2bf(acc[j]);
  *(us8_t*)(A1h + (size_t)r * 2048 + colb) = o;
}

// ---------------- bf16 transpose (32x32 LDS tiles) ----------------
__global__ __launch_bounds__(256) void k_tr_b(const unsigned short* __restrict__ S,
                                              unsigned short* __restrict__ D, int R, int C){
  __shared__ unsigned short t[32][33];
  int bx = blockIdx.x * 32, by = blockIdx.y * 32;
  int tx = threadIdx.x & 31, ty = threadIdx.x >> 5;
#pragma unroll
  for (int i = 0; i < 4; ++i)
    t[ty + i * 8][tx] = S[(size_t)(by + ty + i * 8) * C + bx + tx];
  __syncthreads();
#pragma unroll
  for (int i = 0; i < 4; ++i)
    D[(size_t)(bx + ty + i * 8) * R + by + tx] = t[tx][ty + i * 8];
}

template<int SRCL>
__global__ void k_dinv_bf(const unsigned short* __restrict__ Ah,
                          const unsigned short* __restrict__ Al,
                          float* __restrict__ dinv, int n){
  int row = blockIdx.x;
  float s = 0.f;
  for (int j = threadIdx.x; j < n; j += 256){
    float v = bf2f(Ah[(size_t)row * n + j]);
    if (SRCL) v += bf2f(Al[(size_t)row * n + j]);
    s += v;
  }
  s = waveReduceSum(s);
  __shared__ float sh[4];
  int lane = threadIdx.x & 63, wid = threadIdx.x >> 6;
  if (lane == 0) sh[wid] = s;
  __syncthreads();
  if (threadIdx.x == 0){
    float d = sh[0] + sh[1] + sh[2] + sh[3] + 2.0f;
    dinv[row] = (d > 0.f) ? (1.0f / sqrtf(d)) : 0.0f;
  }
}

// ---------------- MFMA GEMM (unchanged from round 2) ----------------
template<int HAS_AL, int HAS_BL, int HAS_LL, int EPI>
__global__ __launch_bounds__(256) void k_mm(
    const unsigned short* __restrict__ Ah, const unsigned short* __restrict__ Al,
    const unsigned short* __restrict__ Bh, const unsigned short* __restrict__ Bl,
    int M, int N, int K,
    float* __restrict__ Cf, unsigned short* __restrict__ Ch, unsigned short* __restrict__ Cl,
    const float* __restrict__ dinv, const float* __restrict__ Zs,
    const float* __restrict__ bias, int relu)
{
  __shared__ unsigned short lds[16384];
  char* LAH = (char*)lds;
  char* LAL = LAH + 8192;
  char* LBH = LAH + 16384;
  char* LBL = LAH + 24576;

  const int tid = threadIdx.x, lane = tid & 63, wid = tid >> 6;
  const int wm = wid >> 1, wn = wid & 1;
  const int bm = blockIdx.y << 6, bn = blockIdx.x << 6;
  const int l15 = lane & 15, l4 = lane >> 4;

  f4_t acc[2][2];
#pragma unroll
  for (int i = 0; i < 2; ++i)
#pragma unroll
    for (int j = 0; j < 2; ++j) acc[i][j] = (f4_t){0.f, 0.f, 0.f, 0.f};

  const size_t rb = (size_t)K * 2;
  const char* pAh = (const char*)Ah + (size_t)bm * rb;
  const char* pAl = HAS_AL ? (const char*)Al + (size_t)bm * rb : nullptr;
  const char* pBh = (const char*)Bh + (size_t)bn * rb;
  const char* pBl = HAS_BL ? (const char*)Bl + (size_t)bn * rb : nullptr;

  for (int k0 = 0; k0 < K; k0 += 64){
    __syncthreads();
    const size_t kbase = (size_t)k0 * 2;
#pragma unroll
    for (int it = 0; it < 2; ++it){
      const int c = tid + (it << 8);
      const int row = c >> 3, kc = (c & 7) << 4;
      const int off = row * 128 + (kc ^ ((row & 7) << 4));
      const size_t go = (size_t)row * rb + kbase + kc;
      *(int4*)(LAH + off) = *(const int4*)(pAh + go);
      if (HAS_AL) *(int4*)(LAL + off) = *(const int4*)(pAl + go);
      *(int4*)(LBH + off) = *(const int4*)(pBh + go);
      if (HAS_BL) *(int4*)(LBL + off) = *(const int4*)(pBl + go);
    }
    __syncthreads();
#pragma unroll
    for (int ks = 0; ks < 2; ++ks){
      bf8_t aH[2], aL[2], bH[2], bL[2];
#pragma unroll
      for (int f = 0; f < 2; ++f){
        int ar = wm * 32 + f * 16 + l15;
        int ao = ar * 128 + (((ks * 64) + (l4 << 4)) ^ ((ar & 7) << 4));
        aH[f] = *(const bf8_t*)(LAH + ao);
        if (HAS_AL) aL[f] = *(const bf8_t*)(LAL + ao);
        int br = wn * 32 + f * 16 + l15;
        int bo = br * 128 + (((ks * 64) + (l4 << 4)) ^ ((br & 7) << 4));
        bH[f] = *(const bf8_t*)(LBH + bo);
        if (HAS_BL) bL[f] = *(const bf8_t*)(LBL + bo);
      }
#pragma unroll
      for (int i = 0; i < 2; ++i)
#pragma unroll
        for (int j = 0; j < 2; ++j){
          acc[i][j] = __builtin_amdgcn_mfma_f32_16x16x32_bf16(aH[i], bH[j], acc[i][j], 0, 0, 0);
          if (HAS_BL) acc[i][j] = __builtin_amdgcn_mfma_f32_16x16x32_bf16(aH[i], bL[j], acc[i][j], 0, 0, 0);
          if (HAS_AL) acc[i][j] = __builtin_amdgcn_mfma_f32_16x16x32_bf16(aL[i], bH[j], acc[i][j], 0, 0, 0);
          if (HAS_LL) acc[i][j] = __builtin_amdgcn_mfma_f32_16x16x32_bf16(aL[i], bL[j], acc[i][j], 0, 0, 0);
        }
    }
  }

#pragma unroll
  for (int i = 0; i < 2; ++i)
#pragma unroll
    for (int j = 0; j < 2; ++j)
#pragma unroll
      for (int r = 0; r < 4; ++r){
        int grow = bm + wm * 32 + i * 16 + l4 * 4 + r;
        int gcol = bn + wn * 32 + j * 16 + l15;
        float v = acc[i][j][r];
        size_t o = (size_t)grow * N + gcol;
        if (EPI == 0){
          Cf[o] = v;
        } else if (EPI == 1){
          unsigned short h = f2bf(v);
          Ch[o] = h; Cl[o] = f2bf(v - bf2f(h));
        } else if (EPI == 2){
          Cf[o] = dinv[grow] * v;
        } else {
          float out = dinv[grow] * (v + 2.0f * Zs[o]) + bias[gcol];
          if (relu) out = fmaxf(out, 0.f);
          Cf[o] = out;
        }
      }
}

// ---------------- elementwise helpers ----------------
__global__ void k_split(const float* __restrict__ X, unsigned short* __restrict__ H,
                        unsigned short* __restrict__ L, int n){
  int i = blockIdx.x * 256 + threadIdx.x;
  if (i < n){
    float v = X[i];
    unsigned short h = f2bf(v);
    H[i] = h; L[i] = f2bf(v - bf2f(h));
  }
}

__global__ __launch_bounds__(256) void k_tsplit(const float* __restrict__ X, int R, int C,
                                                unsigned short* __restrict__ Th,
                                                unsigned short* __restrict__ Tl){
  __shared__ float t[32][33];
  int bx = blockIdx.x * 32;
  int by = blockIdx.y * 32;
  int tx = threadIdx.x & 31, ty = threadIdx.x >> 5;
#pragma unroll
  for (int i = 0; i < 4; ++i)
    t[ty + i * 8][tx] = X[(size_t)(by + ty + i * 8) * C + bx + tx];
  __syncthreads();
#pragma unroll
  for (int i = 0; i < 4; ++i){
    float v = t[tx][ty + i * 8];
    unsigned short h = f2bf(v);
    size_t o = (size_t)(bx + ty + i * 8) * R + by + tx;
    Th[o] = h; Tl[o] = f2bf(v - bf2f(h));
  }
}

__global__ void k_wnorm(const float* __restrict__ w, float* __restrict__ out){
  float v = w[threadIdx.x]; v *= v;
  v = waveReduceSum(v);
  __shared__ float sh[4];
  int lane = threadIdx.x & 63, wid = threadIdx.x >> 6;
  if (lane == 0) sh[wid] = v;
  __syncthreads();
  if (threadIdx.x == 0) out[0] = sqrtf(sh[0] + sh[1] + sh[2] + sh[3]);
}

__global__ void k_score(const float* __restrict__ x, const float* __restrict__ w,
                        const float* __restrict__ wn, float* __restrict__ score){
  int row = blockIdx.x;
  float v = x[(size_t)row * HID + threadIdx.x] * w[threadIdx.x];
  v = waveReduceSum(v);
  __shared__ float sh[4];
  int lane = threadIdx.x & 63, wid = threadIdx.x >> 6;
  if (lane == 0) sh[wid] = v;
  __syncthreads();
  if (threadIdx.x == 0) score[row] = tanhf((sh[0] + sh[1] + sh[2] + sh[3]) / wn[0]);
}

__global__ void k_topk(const float* __restrict__ score, int n, int k, int* __restrict__ perm){
  int i = blockIdx.x; float si = score[i];
  int cnt = 0;
  for (int j = threadIdx.x; j < n; j += 256){
    float sj = score[j];
    if (sj > si || (sj == si && j < i)) cnt++;
  }
#pragma unroll
  for (int off = 32; off > 0; off >>= 1) cnt += __shfl_down(cnt, off);
  __shared__ int sh[4];
  int lane = threadIdx.x & 63, wid = threadIdx.x >> 6;
  if (lane == 0) sh[wid] = cnt;
  __syncthreads();
  if (threadIdx.x == 0){
    int rank = sh[0] + sh[1] + sh[2] + sh[3];
    if (rank < k) perm[rank] = i;
  }
}

__global__ void k_pool_x2(const float* __restrict__ x, const float* __restrict__ score,
                          const int* __restrict__ perm,
                          unsigned short* __restrict__ xh, unsigned short* __restrict__ xl, int C){
  int r = blockIdx.x; int pr = perm[r]; float s = score[pr];
  for (int c = threadIdx.x; c < C; c += 256){
    float v = x[(size_t)pr * C + c] * s;
    unsigned short h = f2bf(v);
    xh[(size_t)r * C + c] = h;
    xl[(size_t)r * C + c] = f2bf(v - bf2f(h));
  }
}

// D[r][c] = (Sh+Sl)[perm[r]][c] + (perm[r]==c), resplit
template<int SRCL, int OUTL>
__global__ void k_grow_b(const unsigned short* __restrict__ Sh, const unsigned short* __restrict__ Sl,
                         const int* __restrict__ perm,
                         unsigned short* __restrict__ Dh, unsigned short* __restrict__ Dl, int n){
  int r = blockIdx.x, pr = perm[r];
  for (int c = threadIdx.x; c < n; c += 256){
    float v = bf2f(Sh[(size_t)pr * n + c]);
    if (SRCL) v += bf2f(Sl[(size_t)pr * n + c]);
    if (pr == c) v += 1.f;
    unsigned short h = f2bf(v);
    Dh[(size_t)r * n + c] = h;
    if (OUTL) Dl[(size_t)r * n + c] = f2bf(v - bf2f(h));
  }
}

__global__ void k_zdiag_b(unsigned short* __restrict__ H, unsigned short* __restrict__ L, int n){
  int i = blockIdx.x * blockDim.x + threadIdx.x;
  if (i < n){ H[(size_t)i * n + i] = 0; if (L) L[(size_t)i * n + i] = 0; }
}

__global__ void k_unpool_add(float* __restrict__ buf, const float* __restrict__ xs,
                             const int* __restrict__ perm, int C){
  int i = blockIdx.x; int p = perm[i];
  for (int c = threadIdx.x; c < C; c += 256)
    buf[(size_t)p * C + c] += xs[(size_t)i * C + c];
}

// ---------------- host orchestration ----------------
extern "C" void kernel_launch(void* const* d_in, const int* in_sizes, int n_in,
                              void* d_out, int out_size, void* d_ws, size_t ws_size,
                              hipStream_t stream){
  (void)in_sizes; (void)n_in; (void)out_size;
  const float* x_in = (const float*)d_in[0];
  const int*   ei   = (const int*)d_in[1];
  const float* dW0 = (const float*)d_in[2];
  const float* dW1 = (const float*)d_in[3];
  const float* dW2 = (const float*)d_in[4];
  const float* dW3 = (const float*)d_in[5];
  const float* db0 = (const float*)d_in[6];
  const float* db1 = (const float*)d_in[7];
  const float* db2 = (const float*)d_in[8];
  const float* db3 = (const float*)d_in[9];
  const float* pw0 = (const float*)d_in[10];
  const float* pw1 = (const float*)d_in[11];
  const float* pw2 = (const float*)d_in[12];
  const float* uW0 = (const float*)d_in[13];
  const float* uW1 = (const float*)d_in[14];
  const float* uW2 = (const float*)d_in[15];
  const float* ub0 = (const float*)d_in[16];
  const float* ub1 = (const float*)d_in[17];
  const float* ub2 = (const float*)d_in[18];

  char* p = (char*)d_ws;
  auto alloc = [&](size_t nbytes) -> void* {
    void* q = (void*)p; p += (nbytes + 255) & ~(size_t)255; return q;
  };
  unsigned* bits = (unsigned*)alloc((size_t)4096 * 128 * 4);   // 2 MB
  int* ell = (int*)alloc((size_t)4096 * ECAP * 4);             // 2 MB
  int* cnt = (int*)alloc(4096 * 4);
  int* invsel = (int*)alloc(4096 * 4);
  char* RB = (char*)alloc((size_t)32 * 1024 * 1024);           // arena
  unsigned short* Rb  = (unsigned short*)alloc((size_t)4096 * 2048 * 2); // 16 MB
  unsigned short* A1h = (unsigned short*)alloc((size_t)2048 * 2048 * 2);
  unsigned short* A2h = (unsigned short*)alloc((size_t)1024 * 1024 * 2);
  unsigned short* A2l = (unsigned short*)alloc((size_t)1024 * 1024 * 2);
  unsigned short* A3h = (unsigned short*)alloc((size_t)512 * 512 * 2);
  unsigned short* A3l = (unsigned short*)alloc((size_t)512 * 512 * 2);
  float* x0 = (float*)alloc((size_t)4096 * HID * 4);
  float* x1 = (float*)alloc((size_t)2048 * HID * 4);
  float* x2 = (float*)alloc((size_t)1024 * HID * 4);
  float* xv = (float*)alloc((size_t)2048 * HID * 4);
  float* xu = (float*)alloc((size_t)4096 * HID * 4);
  unsigned short* xuh = (unsigned short*)alloc((size_t)4096 * HID * 2);
  unsigned short* xul = (unsigned short*)alloc((size_t)4096 * HID * 2);
  unsigned short* xph = (unsigned short*)alloc((size_t)2048 * HID * 2);
  unsigned short* xpl = (unsigned short*)alloc((size_t)2048 * HID * 2);
  unsigned short* Wth = (unsigned short*)alloc((size_t)512 * 256 * 2);
  unsigned short* Wtl = (unsigned short*)alloc((size_t)512 * 256 * 2);
  float* Zs  = (float*)alloc((size_t)4096 * HID * 4);
  unsigned short* ZsTh = (unsigned short*)alloc((size_t)256 * 2048 * 2);
  unsigned short* ZsTl = (unsigned short*)alloc((size_t)256 * 2048 * 2);
  float* dinv0 = (float*)alloc(4096 * 4);
  float* dinv1 = (float*)alloc(2048 * 4);
  float* dinv2 = (float*)alloc(1024 * 4);
  float* dinv3 = (float*)alloc(512 * 4);
  float* score = (float*)alloc(4096 * 4);
  float* wn    = (float*)alloc(256);
  int* perm1 = (int*)alloc(2048 * 4);
  int* perm2 = (int*)alloc(1024 * 4);
  int* perm3 = (int*)alloc(512 * 4);
  if ((size_t)(p - (char*)d_ws) > ws_size) return;

  // RB arena (time-disjoint phases):
  unsigned short* xinh = (unsigned short*)(RB);                              // conv0
  unsigned short* xinl = (unsigned short*)(RB + (size_t)4 * 1024 * 1024);
  unsigned short* Lb2h = (unsigned short*)(RB);                              // pool2
  unsigned short* Rt2h = (unsigned short*)(RB + (size_t)4 * 1024 * 1024);
  unsigned short* A1T  = (unsigned short*)(RB + (size_t)8 * 1024 * 1024);    // pool2 (8 MB)
  unsigned short* Lb3h = (unsigned short*)(RB + (size_t)16 * 1024 * 1024);   // pool3
  unsigned short* Lb3l = (unsigned short*)(RB + (size_t)17 * 1024 * 1024);
  unsigned short* Rt3h = (unsigned short*)(RB + (size_t)18 * 1024 * 1024);
  unsigned short* Rt3l = (unsigned short*)(RB + (size_t)19 * 1024 * 1024);
  unsigned short* A2Th = (unsigned short*)(RB + (size_t)20 * 1024 * 1024);
  unsigned short* A2Tl = (unsigned short*)(RB + (size_t)22 * 1024 * 1024);

  auto tsplit = [&](const float* X, int R, int C, unsigned short* Th, unsigned short* Tl){
    dim3 g(C / 32, R / 32);
    k_tsplit<<<g, 256, 0, stream>>>(X, R, C, Th, Tl);
  };

  // ================= build graph (bitmask + ELL) =================
  hipMemsetAsync(bits, 0, (size_t)4096 * 128 * 4, stream);
  k_build_bits<<<EE / 256, 256, 0, stream>>>(ei, bits);
  k_ell<<<4096, 128, 0, stream>>>(bits, ell, cnt, dinv0);

  // ================= level-0 conv (sparse) =================
  k_split<<<(4096 * 512 + 255) / 256, 256, 0, stream>>>(x_in, xinh, xinl, 4096 * 512);
  tsplit(dW0, IN_DIM, HID, Wth, Wtl);
  { dim3 g(HID / 64, 4096 / 64);
    k_mm<1,1,0,2><<<g, 256, 0, stream>>>(xinh, xinl, Wth, Wtl, 4096, HID, IN_DIM,
                                         Zs, nullptr, nullptr, dinv0, nullptr, nullptr, 0); }
  k_spmm_ell<256,1><<<4096, 256, 0, stream>>>(ell, cnt, Zs, dinv0, db0, x0);

  // ================= pool 1 (4096 -> 2048) =================
  k_wnorm<<<1, 256, 0, stream>>>(pw0, wn);
  k_score<<<4096, 256, 0, stream>>>(x0, pw0, wn, score);
  k_topk<<<4096, 256, 0, stream>>>(score, 4096, 2048, perm1);
  k_invsel_init<<<16, 256, 0, stream>>>(invsel, 4096);
  k_invsel_set<<<8, 256, 0, stream>>>(perm1, invsel, 2048);
  k_build_Rb<<<4096, 256, 0, stream>>>(ell, cnt, invsel, Rb);
  k_sq1<<<2048, 256, 0, stream>>>(ell, cnt, perm1, Rb, A1h);
  k_zdiag_b<<<8, 256, 0, stream>>>(A1h, nullptr, 2048);
  k_pool_x2<<<2048, 256, 0, stream>>>(x0, score, perm1, xph, xpl, HID);
  k_dinv_bf<0><<<2048, 256, 0, stream>>>(A1h, nullptr, dinv1, 2048);
  tsplit(dW1, HID, HID, Wth, Wtl);
  { dim3 g(HID / 64, 2048 / 64);
    k_mm<1,1,0,2><<<g, 256, 0, stream>>>(xph, xpl, Wth, Wtl, 2048, HID, HID,
                                         Zs, nullptr, nullptr, dinv1, nullptr, nullptr, 0); }
  tsplit(Zs, 2048, HID, ZsTh, ZsTl);
  { dim3 g(HID / 64, 2048 / 64);
    k_mm<0,1,0,3><<<g, 256, 0, stream>>>(A1h, nullptr, ZsTh, ZsTl, 2048, HID, 2048,
                                         x1, nullptr, nullptr, dinv1, Zs, db1, 1); }

  // ================= pool 2 (2048 -> 1024) =================
  k_wnorm<<<1, 256, 0, stream>>>(pw1, wn);
  k_score<<<2048, 256, 0, stream>>>(x1, pw1, wn, score);
  k_topk<<<2048, 256, 0, stream>>>(score, 2048, 1024, perm2);
  { dim3 g(64, 64); k_tr_b<<<g, 256, 0, stream>>>(A1h, A1T, 2048, 2048); }
  k_grow_b<0,0><<<1024, 256, 0, stream>>>(A1h, nullptr, perm2, Lb2h, nullptr, 2048);
  k_grow_b<0,0><<<1024, 256, 0, stream>>>(A1T, nullptr, perm2, Rt2h, nullptr, 2048);
  { dim3 g(1024 / 64, 1024 / 64);
    k_mm<0,0,0,1><<<g, 256, 0, stream>>>(Lb2h, nullptr, Rt2h, nullptr, 1024, 1024, 2048,
                                         nullptr, A2h, A2l, nullptr, nullptr, nullptr, 0); }
  k_zdiag_b<<<4, 256, 0, stream>>>(A2h, A2l, 1024);
  k_pool_x2<<<1024, 256, 0, stream>>>(x1, score, perm2, xph, xpl, HID);
  k_dinv_bf<1><<<1024, 256, 0, stream>>>(A2h, A2l, dinv2, 1024);
  tsplit(dW2, HID, HID, Wth, Wtl);
  { dim3 g(HID / 64, 1024 / 64);
    k_mm<1,1,0,2><<<g, 256, 0, stream>>>(xph, xpl, Wth, Wtl, 1024, HID, HID,
                                         Zs, nullptr, nullptr, dinv2, nullptr, nullptr, 0); }
  tsplit(Zs, 1024, HID, ZsTh, ZsTl);
  { dim3 g(HID / 64, 1024 / 64);
    k_mm<1,1,0,3><<<g, 256, 0, stream>>>(A2h, A2l, ZsTh, ZsTl, 1024, HID, 1024,
                                         x2, nullptr, nullptr, dinv2, Zs, db2, 1); }

  // ================= pool 3 (1024 -> 512) =================
  k_wnorm<<<1, 256, 0, stream>>>(pw2, wn);
  k_score<<<1024, 256, 0, stream>>>(x2, pw2, wn, score);
  k_topk<<<1024, 256, 0, stream>>>(score, 1024, 512, perm3);
  { dim3 g(32, 32); k_tr_b<<<g, 256, 0, stream>>>(A2h, A2Th, 1024, 1024); }
  { dim3 g(32, 32); k_tr_b<<<g, 256, 0, stream>>>(A2l, A2Tl, 1024, 1024); }
  k_grow_b<1,1><<<512, 256, 0, stream>>>(A2h, A2l, perm3, Lb3h, Lb3l, 1024);
  k_grow_b<1,1><<<512, 256, 0, stream>>>(A2Th, A2Tl, perm3, Rt3h, Rt3l, 1024);
  { dim3 g(512 / 64, 512 / 64);
    k_mm<1,1,1,1><<<g, 256, 0, stream>>>(Lb3h, Lb3l, Rt3h, Rt3l, 512, 512, 1024,
                                         nullptr, A3h, A3l, nullptr, nullptr, nullptr, 0); }
  k_zdiag_b<<<2, 256, 0, stream>>>(A3h, A3l, 512);
  k_pool_x2<<<512, 256, 0, stream>>>(x2, score, perm3, xph, xpl, HID);
  k_dinv_bf<1><<<512, 256, 0, stream>>>(A3h, A3l, dinv3, 512);
  tsplit(dW3, HID, HID, Wth, Wtl);
  { dim3 g(HID / 64, 512 / 64);
    k_mm<1,1,0,2><<<g, 256, 0, stream>>>(xph, xpl, Wth, Wtl, 512, HID, HID,
                                         Zs, nullptr, nullptr, dinv3, nullptr, nullptr, 0); }
  tsplit(Zs, 512, HID, ZsTh, ZsTl);
  { dim3 g(HID / 64, 512 / 64);
    k_mm<1,1,0,3><<<g, 256, 0, stream>>>(A3h, A3l, ZsTh, ZsTl, 512, HID, 512,
                                         xv, nullptr, nullptr, dinv3, Zs, db3, 1); }  // xv = x3

  // ================= up 0 (res=x2, perm3, A2) =================
  hipMemcpyAsync(xu, x2, (size_t)1024 * HID * 4, hipMemcpyDeviceToDevice, stream);
  k_unpool_add<<<512, 256, 0, stream>>>(xu, xv, perm3, HID);
  k_split<<<(1024 * HID + 255) / 256, 256, 0, stream>>>(xu, xuh, xul, 1024 * HID);
  tsplit(uW0, HID, HID, Wth, Wtl);
  { dim3 g(HID / 64, 1024 / 64);
    k_mm<1,1,0,2><<<g, 256, 0, stream>>>(xuh, xul, Wth, Wtl, 1024, HID, HID,
                                         Zs, nullptr, nullptr, dinv2, nullptr, nullptr, 0); }
  tsplit(Zs, 1024, HID, ZsTh, ZsTl);
  { dim3 g(HID / 64, 1024 / 64);
    k_mm<1,1,0,3><<<g, 256, 0, stream>>>(A2h, A2l, ZsTh, ZsTl, 1024, HID, 1024,
                                         xv, nullptr, nullptr, dinv2, Zs, ub0, 1); }

  // ================= up 1 (res=x1, perm2, A1) =================
  hipMemcpyAsync(xu, x1, (size_t)2048 * HID * 4, hipMemcpyDeviceToDevice, stream);
  k_unpool_add<<<1024, 256, 0, stream>>>(xu, xv, perm2, HID);
  k_split<<<(2048 * HID + 255) / 256, 256, 0, stream>>>(xu, xuh, xul, 2048 * HID);
  tsplit(uW1, HID, HID, Wth, Wtl);
  { dim3 g(HID / 64, 2048 / 64);
    k_mm<1,1,0,2><<<g, 256, 0, stream>>>(xuh, xul, Wth, Wtl, 2048, HID, HID,
                                         Zs, nullptr, nullptr, dinv1, nullptr, nullptr, 0); }
  tsplit(Zs, 2048, HID, ZsTh, ZsTl);
  { dim3 g(HID / 64, 2048 / 64);
    k_mm<0,1,0,3><<<g, 256, 0, stream>>>(A1h, nullptr, ZsTh, ZsTl, 2048, HID, 2048,
                                         xv, nullptr, nullptr, dinv1, Zs, ub1, 1); }

  // ================= up 2 (res=x0, perm1, A0 sparse, Cout=64, no relu) =================
  hipMemcpyAsync(xu, x0, (size_t)4096 * HID * 4, hipMemcpyDeviceToDevice, stream);
  k_unpool_add<<<2048, 256, 0, stream>>>(xu, xv, perm1, HID);
  k_split<<<(4096 * HID + 255) / 256, 256, 0, stream>>>(xu, xuh, xul, 4096 * HID);
  tsplit(uW2, HID, OUT_DIM, Wth, Wtl);
  { dim3 g(OUT_DIM / 64, 4096 / 64);
    k_mm<1,1,0,2><<<g, 256, 0, stream>>>(xuh, xul, Wth, Wtl, 4096, OUT_DIM, HID,
                                         Zs, nullptr, nullptr, dinv0, nullptr, nullptr, 0); }
  k_spmm_ell<64,0><<<4096, 256, 0, stream>>>(ell, cnt, Zs, dinv0, ub2, (float*)d_out);
}